// Round 5
// baseline (1082.708 us; speedup 1.0000x reference)
//
#include <hip/hip_runtime.h>
#include <hip/hip_bf16.h>

typedef __attribute__((ext_vector_type(8))) short short8;
typedef __attribute__((ext_vector_type(4))) float f32x4;
typedef unsigned int uint32;

// async global->LDS, 16B per lane; LDS dest = uniform base + lane*16
#define GLD16(g, l) __builtin_amdgcn_global_load_lds( \
    (const __attribute__((address_space(1))) unsigned int*)(g), \
    (__attribute__((address_space(3))) unsigned int*)(l), 16, 0, 0)

__device__ __forceinline__ float bfu(unsigned short u) {
    union { uint32 v; float f; } x; x.v = ((uint32)u) << 16; return x.f;
}
__device__ __forceinline__ void storev(float* p, float v) { *p = v; }
__device__ __forceinline__ void storev(__hip_bfloat16* p, float v) { *p = __float2bfloat16(v); }

// ============ transpose fp32 [K,N] -> bf16 [N,K] ============
__global__ __launch_bounds__(256) void transpose_bf16(
    const float* __restrict__ W, __hip_bfloat16* __restrict__ WT, int K, int N)
{
    __shared__ float tile[32][33];
    int k0 = blockIdx.x * 32, n0 = blockIdx.y * 32;
    int tx = threadIdx.x & 31, ty = threadIdx.x >> 5;   // 32 x 8
    #pragma unroll
    for (int i = 0; i < 32; i += 8)
        tile[ty + i][tx] = W[(size_t)(k0 + ty + i) * N + n0 + tx];
    __syncthreads();
    #pragma unroll
    for (int i = 0; i < 32; i += 8)
        WT[(size_t)(n0 + ty + i) * K + k0 + tx] = __float2bfloat16(tile[tx][ty + i]);
}

// ============ encoders ============
__global__ __launch_bounds__(256) void encode_nodes(
    const float* __restrict__ x, const float* __restrict__ Wn,
    const float* __restrict__ bn, __hip_bfloat16* __restrict__ h, int Nn)
{
    int idx = blockIdx.x * 256 + threadIdx.x;
    if (idx >= Nn * 512) return;
    int n = idx >> 9, c = idx & 511;
    float acc = bn[c];
    #pragma unroll
    for (int f = 0; f < 7; ++f) acc += x[n * 7 + f] * Wn[f * 512 + c];
    h[idx] = __float2bfloat16(fmaxf(acc, 0.f));
}

__global__ __launch_bounds__(256) void encode_edges(
    const float* __restrict__ eat, const float* __restrict__ We,
    const float* __restrict__ be, __hip_bfloat16* __restrict__ ea, int E)
{
    int idx = blockIdx.x * 256 + threadIdx.x;
    if (idx >= E * 512) return;
    int e = idx >> 9, c = idx & 511;
    float v = fmaf(eat[e * 2], We[c], fmaf(eat[e * 2 + 1], We[512 + c], be[c]));
    ea[idx] = __float2bfloat16(fmaxf(v, 0.f));
}

// ============ bf16 MFMA GEMM, m97-style global_load_lds staging ============
template <typename OutT, bool HAS_BIAS>
__global__ __launch_bounds__(256) void mfma_gemm(
    const __hip_bfloat16* __restrict__ A, int lda, long az,
    const __hip_bfloat16* __restrict__ BT, int ldb, long bz,
    const float* __restrict__ bias,
    OutT* __restrict__ C, int ldc, long cz, int M, int K)
{
    __shared__ uint4 As4[512];   // 8 KB
    __shared__ uint4 Bs4[512];
    A  += (long)blockIdx.z * az;
    BT += (long)blockIdx.z * bz;
    C  += (long)blockIdx.z * cz;
    const int t = threadIdx.x, lane = t & 63, w = t >> 6;
    const int wr = (w >> 1) * 64, wc = (w & 1) * 64;
    const int row0 = blockIdx.x * 128, col0 = blockIdx.y * 128;
    const int lr = lane & 15, lg = lane >> 4;
    const int r0 = w * 16 + (lane >> 2);                     // staging row, seg w
    const int ksw = ((lane & 3) ^ ((lane >> 3) & 3)) * 8;    // swizzled k-chunk (elems)
    const int rsw = (lg ^ ((lr >> 1) & 3)) << 4;             // read-side swizzle (bytes)

    const __hip_bfloat16* Ap0 = A + (size_t)(row0 + r0) * lda + ksw;
    const __hip_bfloat16* Ap1 = A + (size_t)(row0 + r0 + 64) * lda + ksw;
    const __hip_bfloat16* Bp0 = BT + (size_t)(col0 + r0) * ldb + ksw;
    const __hip_bfloat16* Bp1 = BT + (size_t)(col0 + r0 + 64) * ldb + ksw;
    char* AsB = (char*)As4; char* BsB = (char*)Bs4;
    uint4* la0 = As4 + w * 64;       uint4* la1 = As4 + (w + 4) * 64;
    uint4* lb0 = Bs4 + w * 64;       uint4* lb1 = Bs4 + (w + 4) * 64;

    f32x4 acc[4][4];
    #pragma unroll
    for (int m = 0; m < 4; ++m)
        #pragma unroll
        for (int n = 0; n < 4; ++n) acc[m][n] = 0.f;

    for (int k0 = 0; k0 < K; k0 += 32) {
        GLD16(Ap0 + k0, la0);
        GLD16(Ap1 + k0, la1);
        GLD16(Bp0 + k0, lb0);
        GLD16(Bp1 + k0, lb1);
        __syncthreads();
        short8 af[4], bfrag[4];
        #pragma unroll
        for (int m = 0; m < 4; ++m)
            af[m] = *(const short8*)(AsB + (wr + m * 16 + lr) * 64 + rsw);
        #pragma unroll
        for (int n = 0; n < 4; ++n)
            bfrag[n] = *(const short8*)(BsB + (wc + n * 16 + lr) * 64 + rsw);
        #pragma unroll
        for (int m = 0; m < 4; ++m)
            #pragma unroll
            for (int n = 0; n < 4; ++n)
                acc[m][n] = __builtin_amdgcn_mfma_f32_16x16x32_bf16(af[m], bfrag[n], acc[m][n], 0, 0, 0);
        __syncthreads();
    }

    #pragma unroll
    for (int m = 0; m < 4; ++m) {
        #pragma unroll
        for (int r = 0; r < 4; ++r) {
            int gr = row0 + wr + m * 16 + lg * 4 + r;
            if (gr >= M) continue;
            #pragma unroll
            for (int n = 0; n < 4; ++n) {
                int gc = col0 + wc + n * 16 + lr;
                float v = acc[m][n][r];
                if (HAS_BIAS) v += bias[gc];
                storev(&C[(size_t)gr * ldc + gc], v);
            }
        }
    }
}

// ============ edge GEMM + fused logits, one block owns 128 edges x 1 head ======
// grid (EP/128, 4). Block loops over the head's 4 col-tiles; ea read once (L2
// for repeats), XL/XR rows walked sequentially 256B/tile; logits plain-stored.
__global__ __launch_bounds__(256) void edge_mfma_logits(
    const __hip_bfloat16* __restrict__ ea,    // [EP,512]
    const __hip_bfloat16* __restrict__ WleT,  // [2048,512]
    const __hip_bfloat16* __restrict__ XL,
    const __hip_bfloat16* __restrict__ XR,
    const int* __restrict__ ei,
    const float* __restrict__ att,
    float* __restrict__ logits,               // [E,4] plain store
    int E)
{
    __shared__ uint4 As4[512];
    __shared__ uint4 Bs4[512];
    __shared__ int srcs[128], dsts[128];
    __shared__ float fbuf[128];
    const int t = threadIdx.x, lane = t & 63, w = t >> 6;
    const int wr = (w >> 1) * 64, wc = (w & 1) * 64;
    const int row0 = blockIdx.x * 128;
    const int hh = blockIdx.y;
    const int lr = lane & 15, lg = lane >> 4;
    const int r0 = w * 16 + (lane >> 2);
    const int ksw = ((lane & 3) ^ ((lane >> 3) & 3)) * 8;
    const int rsw = (lg ^ ((lr >> 1) & 3)) << 4;

    if (t < 128) {
        int ge = row0 + t;
        bool ok = ge < E;
        srcs[t] = ok ? ei[ge] : 0;
        dsts[t] = ok ? ei[E + ge] : 0;
    }
    char* AsB = (char*)As4; char* BsB = (char*)Bs4;
    uint4* la0 = As4 + w * 64;       uint4* la1 = As4 + (w + 4) * 64;
    uint4* lb0 = Bs4 + w * 64;       uint4* lb1 = Bs4 + (w + 4) * 64;
    const __hip_bfloat16* Ap0 = ea + (size_t)(row0 + r0) * 512 + ksw;
    const __hip_bfloat16* Ap1 = ea + (size_t)(row0 + r0 + 64) * 512 + ksw;

    // att values for the 16 (cy,n) columns this lane touches (head hh)
    float attv[4][4];
    #pragma unroll
    for (int cy = 0; cy < 4; ++cy)
        #pragma unroll
        for (int n = 0; n < 4; ++n)
            attv[cy][n] = att[hh * 512 + cy * 128 + wc + n * 16 + lr];

    float part[4][4];
    #pragma unroll
    for (int m = 0; m < 4; ++m)
        #pragma unroll
        for (int r = 0; r < 4; ++r) part[m][r] = 0.f;

    const int prt = (lane & 3) * 8;
    __syncthreads();

    for (int cy = 0; cy < 4; ++cy) {
        const int col0 = (hh * 4 + cy) * 128;
        const __hip_bfloat16* Bp0 = WleT + (size_t)(col0 + r0) * 512 + ksw;
        const __hip_bfloat16* Bp1 = WleT + (size_t)(col0 + r0 + 64) * 512 + ksw;

        f32x4 acc[4][4];
        #pragma unroll
        for (int m = 0; m < 4; ++m)
            #pragma unroll
            for (int n = 0; n < 4; ++n) acc[m][n] = 0.f;

        for (int k0 = 0; k0 < 512; k0 += 32) {
            GLD16(Ap0 + k0, la0);
            GLD16(Ap1 + k0, la1);
            GLD16(Bp0 + k0, lb0);
            GLD16(Bp1 + k0, lb1);
            __syncthreads();
            short8 af[4], bfrag[4];
            #pragma unroll
            for (int m = 0; m < 4; ++m)
                af[m] = *(const short8*)(AsB + (wr + m * 16 + lr) * 64 + rsw);
            #pragma unroll
            for (int n = 0; n < 4; ++n)
                bfrag[n] = *(const short8*)(BsB + (wc + n * 16 + lr) * 64 + rsw);
            #pragma unroll
            for (int m = 0; m < 4; ++m)
                #pragma unroll
                for (int n = 0; n < 4; ++n)
                    acc[m][n] = __builtin_amdgcn_mfma_f32_16x16x32_bf16(af[m], bfrag[n], acc[m][n], 0, 0, 0);
            __syncthreads();
        }

        // logits partial: stage XL/XR 32-col strips into reused As/Bs
        #pragma unroll
        for (int ch = 0; ch < 4; ++ch) {
            int cc = col0 + ch * 32;
            GLD16(XL + (size_t)srcs[r0] * 2048 + cc + prt, la0);
            GLD16(XL + (size_t)srcs[r0 + 64] * 2048 + cc + prt, la1);
            GLD16(XR + (size_t)dsts[r0] * 2048 + cc + prt, lb0);
            GLD16(XR + (size_t)dsts[r0 + 64] * 2048 + cc + prt, lb1);
            __syncthreads();
            #pragma unroll
            for (int n = 0; n < 4; ++n) {
                if (((wc + n * 16) >> 5) != ch) continue;
                int colin = ((n & 1) << 4) + lr;
                #pragma unroll
                for (int m = 0; m < 4; ++m) {
                    #pragma unroll
                    for (int r = 0; r < 4; ++r) {
                        int row = wr + m * 16 + lg * 4 + r;
                        float xl = bfu(*(const unsigned short*)(AsB + row * 64 + colin * 2));
                        float xr = bfu(*(const unsigned short*)(BsB + row * 64 + colin * 2));
                        float mv = acc[m][n][r] + xl + xr;
                        part[m][r] += attv[cy][n] * ((mv > 0.f) ? mv : 0.2f * mv);
                    }
                }
            }
            __syncthreads();
        }
    }

    // reduce within wave (over lr), then combine wave pairs (wc halves) via LDS
    #pragma unroll
    for (int m = 0; m < 4; ++m)
        #pragma unroll
        for (int r = 0; r < 4; ++r) {
            part[m][r] += __shfl_xor(part[m][r], 1);
            part[m][r] += __shfl_xor(part[m][r], 2);
            part[m][r] += __shfl_xor(part[m][r], 4);
            part[m][r] += __shfl_xor(part[m][r], 8);
        }
    if ((w & 1) && lr == 0) {
        #pragma unroll
        for (int m = 0; m < 4; ++m)
            #pragma unroll
            for (int r = 0; r < 4; ++r)
                fbuf[(w >> 1) * 64 + m * 16 + lg * 4 + r] = part[m][r];
    }
    __syncthreads();
    if (!(w & 1) && lr == 0) {
        #pragma unroll
        for (int m = 0; m < 4; ++m)
            #pragma unroll
            for (int r = 0; r < 4; ++r) {
                int ro = m * 16 + lg * 4 + r;
                int ge = row0 + wr + ro;
                if (ge < E)
                    logits[ge * 4 + hh] = part[m][r] + fbuf[(w >> 1) * 64 + ro];
            }
    }
}

// ============ exp + denominator scatter ============
__global__ __launch_bounds__(256) void softmax_den(
    const float* __restrict__ logits, const int* __restrict__ ei,
    float* __restrict__ exb, float* __restrict__ den, int E)
{
    int idx = blockIdx.x * 256 + threadIdx.x;
    if (idx >= E * 4) return;
    int e = idx >> 2, h = idx & 3;
    float ex = expf(logits[idx]);   // softmax shift-invariant; logits O(0.1)
    exb[idx] = ex;
    atomicAdd(&den[ei[E + e] * 4 + h], ex);
}

// ============ Z[dst,:] += sum_h alpha_h * Y[src,h,:] ============
__global__ __launch_bounds__(256) void scatter_z(
    const __hip_bfloat16* __restrict__ Y, const int* __restrict__ ei,
    const float* __restrict__ exb, const float* __restrict__ den,
    float* __restrict__ Z, int E)
{
    int e = blockIdx.x, t = threadIdx.x;
    int src = ei[e], dst = ei[E + e];
    float al[4];
    #pragma unroll
    for (int h = 0; h < 4; ++h)
        al[h] = exb[e * 4 + h] / (den[dst * 4 + h] + 1e-16f);
    int c = t * 2;
    float z0 = 0.f, z1 = 0.f;
    #pragma unroll
    for (int h = 0; h < 4; ++h) {
        uint32 q = *(const uint32*)((const unsigned short*)Y + ((size_t)src * 4 + h) * 512 + c);
        z0 += al[h] * bfu((unsigned short)(q & 0xffff));
        z1 += al[h] * bfu((unsigned short)(q >> 16));
    }
    atomicAdd(&Z[(size_t)dst * 512 + c], z0);
    atomicAdd(&Z[(size_t)dst * 512 + c + 1], z1);
}

// ============ bias2 = b_d1 + conv_bias @ W_d1 ============
__global__ __launch_bounds__(256) void bias2_kernel(
    const float* __restrict__ bd1, const float* __restrict__ cb,
    const float* __restrict__ Wd1, float* __restrict__ bias2)
{
    int j = blockIdx.x * 256 + threadIdx.x;
    if (j >= 512) return;
    float acc = bd1[j];
    for (int k = 0; k < 2048; ++k) acc += cb[k] * Wd1[(size_t)k * 512 + j];
    bias2[j] = acc;
}

// ============ out = sigmoid(relu(Z+bias2) @ W_d2 + b_d2) ============
__global__ __launch_bounds__(256) void decoder(
    const float* __restrict__ Z, const float* __restrict__ bias2,
    const float* __restrict__ Wd2, const float* __restrict__ bd2,
    float* __restrict__ out, int M)
{
    int node = (blockIdx.x * 256 + threadIdx.x) >> 6;
    int lane = threadIdx.x & 63;
    if (node >= M) return;
    const float* zr = Z + (size_t)node * 512;
    float p[6] = {0.f, 0.f, 0.f, 0.f, 0.f, 0.f};
    #pragma unroll
    for (int k = 0; k < 8; ++k) {
        int c = lane + k * 64;
        float a = fmaxf(zr[c] + bias2[c], 0.f);
        #pragma unroll
        for (int j = 0; j < 6; ++j) p[j] += a * Wd2[c * 6 + j];
    }
    #pragma unroll
    for (int off = 32; off; off >>= 1)
        #pragma unroll
        for (int j = 0; j < 6; ++j) p[j] += __shfl_down(p[j], off);
    if (lane == 0) {
        #pragma unroll
        for (int j = 0; j < 6; ++j)
            out[(size_t)node * 6 + j] = 1.f / (1.f + expf(-(p[j] + bd2[j])));
    }
}

extern "C" void kernel_launch(void* const* d_in, const int* in_sizes, int n_in,
                              void* d_out, int out_size, void* d_ws, size_t ws_size,
                              hipStream_t stream)
{
    const float* x         = (const float*)d_in[0];
    const float* edge_attr = (const float*)d_in[1];
    const int*   ei        = (const int*)d_in[2];
    const float* W_node = (const float*)d_in[3],  *b_node = (const float*)d_in[4];
    const float* W_edge = (const float*)d_in[5],  *b_edge = (const float*)d_in[6];
    const float* W_l    = (const float*)d_in[7],  *b_l    = (const float*)d_in[8];
    const float* W_r    = (const float*)d_in[9],  *b_r    = (const float*)d_in[10];
    const float* W_le   = (const float*)d_in[11];
    const float* att    = (const float*)d_in[12];
    const float* conv_bias = (const float*)d_in[13];
    const float* W_d1   = (const float*)d_in[14], *b_d1 = (const float*)d_in[15];
    const float* W_d2   = (const float*)d_in[16], *b_d2 = (const float*)d_in[17];
    float* out = (float*)d_out;

    const int N = in_sizes[0] / 7;   // 25000
    const int E = in_sizes[1] / 2;   // 50000
    const int MP = (N + 127) & ~127; // padded rows (unguarded async A-reads)
    const int EP = (E + 127) & ~127;

    // ---- workspace layout (~267 MB) ----
    char* ws = (char*)d_ws;
    const size_t szR0 = (size_t)EP * 512 * 2;     // h bf16 -> ea bf16 -> Z f32
    const size_t szX  = (size_t)MP * 2048 * 2;
    const size_t szW  = (size_t)2048 * 512 * 2;
    const size_t o_XL = szR0;
    const size_t o_XR = o_XL + szX;
    const size_t o_W  = o_XR + szX;
    const size_t o_lg = o_W + 4 * szW;
    const size_t szlg = (size_t)E * 4 * 4;
    const size_t o_ex = o_lg + szlg;
    const size_t o_dn = o_ex + szlg;
    const size_t o_b2 = o_dn + (size_t)N * 4 * 4;
    const size_t need = o_b2 + 512 * 4;
    if (ws_size < need) return;   // clean diagnostic failure if ws too small

    __hip_bfloat16* h   = (__hip_bfloat16*)ws;
    __hip_bfloat16* ea  = (__hip_bfloat16*)ws;
    float*          Z   = (float*)ws;
    __hip_bfloat16* XL  = (__hip_bfloat16*)(ws + o_XL);
    __hip_bfloat16* XR  = (__hip_bfloat16*)(ws + o_XR);
    __hip_bfloat16* Y   = XR;                       // overlays XR after logits
    __hip_bfloat16* WlT = (__hip_bfloat16*)(ws + o_W);
    __hip_bfloat16* WrT = WlT + szW / 2;
    __hip_bfloat16* WleT= WrT + szW / 2;
    __hip_bfloat16* Wd1T= WleT + szW / 2;
    float* logits = (float*)(ws + o_lg);
    float* exb    = (float*)(ws + o_ex);
    float* den    = (float*)(ws + o_dn);
    float* bias2  = (float*)(ws + o_b2);

    hipMemsetAsync(den, 0, (size_t)N * 4 * 4, stream);

    // weight prep: [K,N] fp32 -> [N,K] bf16
    dim3 gT(512 / 32, 2048 / 32);
    transpose_bf16<<<gT, 256, 0, stream>>>(W_l,  WlT, 512, 2048);
    transpose_bf16<<<gT, 256, 0, stream>>>(W_r,  WrT, 512, 2048);
    transpose_bf16<<<gT, 256, 0, stream>>>(W_le, WleT, 512, 2048);
    dim3 gT2(2048 / 32, 512 / 32);
    transpose_bf16<<<gT2, 256, 0, stream>>>(W_d1, Wd1T, 2048, 512);
    bias2_kernel<<<2, 256, 0, stream>>>(b_d1, conv_bias, W_d1, bias2);

    encode_nodes<<<(N * 512 + 255) / 256, 256, 0, stream>>>(x, W_node, b_node, h, N);

    const int MB = MP / 128;
    dim3 gNode(MB, 2048 / 128);
    mfma_gemm<__hip_bfloat16, true><<<gNode, 256, 0, stream>>>(
        h, 512, 0, WlT, 512, 0, b_l, XL, 2048, 0, N, 512);
    mfma_gemm<__hip_bfloat16, true><<<gNode, 256, 0, stream>>>(
        h, 512, 0, WrT, 512, 0, b_r, XR, 2048, 0, N, 512);

    // h dead -> region0 becomes ea
    encode_edges<<<(E * 512 + 255) / 256, 256, 0, stream>>>(edge_attr, W_edge, b_edge, ea, E);

    dim3 gE(EP / 128, 4);
    edge_mfma_logits<<<gE, 256, 0, stream>>>(ea, WleT, XL, XR, ei, att, logits, E);

    softmax_den<<<(E * 4 + 255) / 256, 256, 0, stream>>>(logits, ei, exb, den, E);

    // Y[n, hh*512+c] = XL[n, hh*512:] @ W_d1[hh*512:, :]  (block-diag, grid.z=4)
    dim3 gY(MB, 512 / 128, 4);
    mfma_gemm<__hip_bfloat16, false><<<gY, 256, 0, stream>>>(
        XL, 2048, 512, Wd1T, 2048, 512, nullptr, Y, 2048, 512, N, 512);

    // ea dead -> region0 becomes Z
    hipMemsetAsync(Z, 0, (size_t)N * 512 * 4, stream);
    scatter_z<<<E, 256, 0, stream>>>(Y, ei, exb, den, Z, E);

    decoder<<<(N * 64 + 255) / 256, 256, 0, stream>>>(Z, bias2, W_d2, b_d2, out, N);
}

// Round 7
// 784.813 us; speedup vs baseline: 1.3796x; 1.3796x over previous
//
#include <hip/hip_runtime.h>
#include <hip/hip_bf16.h>

typedef __attribute__((ext_vector_type(8))) short short8;
typedef __attribute__((ext_vector_type(4))) float f32x4;
typedef unsigned int uint32;

// async global->LDS, 16B per lane; LDS dest = uniform base + lane*16
#define GLD16(g, l) __builtin_amdgcn_global_load_lds( \
    (const __attribute__((address_space(1))) unsigned int*)(g), \
    (__attribute__((address_space(3))) unsigned int*)(l), 16, 0, 0)

__device__ __forceinline__ float bfu(unsigned short u) {
    union { uint32 v; float f; } x; x.v = ((uint32)u) << 16; return x.f;
}
__device__ __forceinline__ void storev(float* p, float v) { *p = v; }
__device__ __forceinline__ void storev(__hip_bfloat16* p, float v) { *p = __float2bfloat16(v); }

// ============ transpose fp32 [K,N] -> bf16 [N,K] ============
__global__ __launch_bounds__(256) void transpose_bf16(
    const float* __restrict__ W, __hip_bfloat16* __restrict__ WT, int K, int N)
{
    __shared__ float tile[32][33];
    int k0 = blockIdx.x * 32, n0 = blockIdx.y * 32;
    int tx = threadIdx.x & 31, ty = threadIdx.x >> 5;   // 32 x 8
    #pragma unroll
    for (int i = 0; i < 32; i += 8)
        tile[ty + i][tx] = W[(size_t)(k0 + ty + i) * N + n0 + tx];
    __syncthreads();
    #pragma unroll
    for (int i = 0; i < 32; i += 8)
        WT[(size_t)(n0 + ty + i) * K + k0 + tx] = __float2bfloat16(tile[tx][ty + i]);
}

// ============ encoders ============
__global__ __launch_bounds__(256) void encode_nodes(
    const float* __restrict__ x, const float* __restrict__ Wn,
    const float* __restrict__ bn, __hip_bfloat16* __restrict__ h, int Nn)
{
    int idx = blockIdx.x * 256 + threadIdx.x;
    if (idx >= Nn * 512) return;
    int n = idx >> 9, c = idx & 511;
    float acc = bn[c];
    #pragma unroll
    for (int f = 0; f < 7; ++f) acc += x[n * 7 + f] * Wn[f * 512 + c];
    h[idx] = __float2bfloat16(fmaxf(acc, 0.f));
}

__global__ __launch_bounds__(256) void encode_edges(
    const float* __restrict__ eat, const float* __restrict__ We,
    const float* __restrict__ be, __hip_bfloat16* __restrict__ ea, int E)
{
    int idx = blockIdx.x * 256 + threadIdx.x;
    if (idx >= E * 512) return;
    int e = idx >> 9, c = idx & 511;
    float v = fmaf(eat[e * 2], We[c], fmaf(eat[e * 2 + 1], We[512 + c], be[c]));
    ea[idx] = __float2bfloat16(fmaxf(v, 0.f));
}

// ============ bf16 MFMA GEMM (grid.x = col tile for temporal A reuse) ============
template <typename OutT, bool HAS_BIAS>
__global__ __launch_bounds__(256) void mfma_gemm(
    const __hip_bfloat16* __restrict__ A, int lda, long az,
    const __hip_bfloat16* __restrict__ BT, int ldb, long bz,
    const float* __restrict__ bias,
    OutT* __restrict__ C, int ldc, long cz, int M, int K)
{
    __shared__ uint4 As4[512];   // 8 KB
    __shared__ uint4 Bs4[512];
    A  += (long)blockIdx.z * az;
    BT += (long)blockIdx.z * bz;
    C  += (long)blockIdx.z * cz;
    const int t = threadIdx.x, lane = t & 63, w = t >> 6;
    const int wr = (w >> 1) * 64, wc = (w & 1) * 64;
    const int col0 = blockIdx.x * 128, row0 = blockIdx.y * 128;  // x = col tile (fast)
    const int lr = lane & 15, lg = lane >> 4;
    const int r0 = w * 16 + (lane >> 2);                     // staging row, seg w
    const int ksw = ((lane & 3) ^ ((lane >> 3) & 3)) * 8;    // swizzled k-chunk (elems)
    const int rsw = (lg ^ ((lr >> 1) & 3)) << 4;             // read-side swizzle (bytes)

    const __hip_bfloat16* Ap0 = A + (size_t)(row0 + r0) * lda + ksw;
    const __hip_bfloat16* Ap1 = A + (size_t)(row0 + r0 + 64) * lda + ksw;
    const __hip_bfloat16* Bp0 = BT + (size_t)(col0 + r0) * ldb + ksw;
    const __hip_bfloat16* Bp1 = BT + (size_t)(col0 + r0 + 64) * ldb + ksw;
    char* AsB = (char*)As4; char* BsB = (char*)Bs4;
    uint4* la0 = As4 + w * 64;       uint4* la1 = As4 + (w + 4) * 64;
    uint4* lb0 = Bs4 + w * 64;       uint4* lb1 = Bs4 + (w + 4) * 64;

    f32x4 acc[4][4];
    #pragma unroll
    for (int m = 0; m < 4; ++m)
        #pragma unroll
        for (int n = 0; n < 4; ++n) acc[m][n] = 0.f;

    for (int k0 = 0; k0 < K; k0 += 32) {
        GLD16(Ap0 + k0, la0);
        GLD16(Ap1 + k0, la1);
        GLD16(Bp0 + k0, lb0);
        GLD16(Bp1 + k0, lb1);
        __syncthreads();
        short8 af[4], bfrag[4];
        #pragma unroll
        for (int m = 0; m < 4; ++m)
            af[m] = *(const short8*)(AsB + (wr + m * 16 + lr) * 64 + rsw);
        #pragma unroll
        for (int n = 0; n < 4; ++n)
            bfrag[n] = *(const short8*)(BsB + (wc + n * 16 + lr) * 64 + rsw);
        #pragma unroll
        for (int m = 0; m < 4; ++m)
            #pragma unroll
            for (int n = 0; n < 4; ++n)
                acc[m][n] = __builtin_amdgcn_mfma_f32_16x16x32_bf16(af[m], bfrag[n], acc[m][n], 0, 0, 0);
        __syncthreads();
    }

    #pragma unroll
    for (int m = 0; m < 4; ++m) {
        #pragma unroll
        for (int r = 0; r < 4; ++r) {
            int gr = row0 + wr + m * 16 + lg * 4 + r;
            if (gr >= M) continue;
            #pragma unroll
            for (int n = 0; n < 4; ++n) {
                int gc = col0 + wc + n * 16 + lr;
                float v = acc[m][n][r];
                if (HAS_BIAS) v += bias[gc];
                storev(&C[(size_t)gr * ldc + gc], v);
            }
        }
    }
}

// ============ edge GEMM + fused logits (grid.x = col tile) ====
__global__ __launch_bounds__(256) void edge_mfma_logits(
    const __hip_bfloat16* __restrict__ ea,    // [EP,512]
    const __hip_bfloat16* __restrict__ WleT,  // [2048,512]
    const __hip_bfloat16* __restrict__ XL,
    const __hip_bfloat16* __restrict__ XR,
    const int* __restrict__ ei,
    const float* __restrict__ att,
    float* __restrict__ logits,               // [E,4] pre-zeroed, atomic partial
    int E)
{
    __shared__ uint4 As4[512];
    __shared__ uint4 Bs4[512];
    __shared__ int srcs[128], dsts[128];
    const int t = threadIdx.x, lane = t & 63, w = t >> 6;
    const int wr = (w >> 1) * 64, wc = (w & 1) * 64;
    const int col0 = blockIdx.x * 128, row0 = blockIdx.y * 128;  // x = col tile (fast)
    const int lr = lane & 15, lg = lane >> 4;
    const int r0 = w * 16 + (lane >> 2);
    const int ksw = ((lane & 3) ^ ((lane >> 3) & 3)) * 8;
    const int rsw = (lg ^ ((lr >> 1) & 3)) << 4;

    if (t < 128) {
        int ge = row0 + t;
        bool ok = ge < E;
        srcs[t] = ok ? ei[ge] : 0;
        dsts[t] = ok ? ei[E + ge] : 0;
    }
    char* AsB = (char*)As4; char* BsB = (char*)Bs4;
    uint4* la0 = As4 + w * 64;       uint4* la1 = As4 + (w + 4) * 64;
    uint4* lb0 = Bs4 + w * 64;       uint4* lb1 = Bs4 + (w + 4) * 64;
    const __hip_bfloat16* Ap0 = ea + (size_t)(row0 + r0) * 512 + ksw;
    const __hip_bfloat16* Ap1 = ea + (size_t)(row0 + r0 + 64) * 512 + ksw;
    const __hip_bfloat16* Bp0 = WleT + (size_t)(col0 + r0) * 512 + ksw;
    const __hip_bfloat16* Bp1 = WleT + (size_t)(col0 + r0 + 64) * 512 + ksw;
    __syncthreads();

    f32x4 acc[4][4];
    #pragma unroll
    for (int m = 0; m < 4; ++m)
        #pragma unroll
        for (int n = 0; n < 4; ++n) acc[m][n] = 0.f;

    for (int k0 = 0; k0 < 512; k0 += 32) {
        GLD16(Ap0 + k0, la0);
        GLD16(Ap1 + k0, la1);
        GLD16(Bp0 + k0, lb0);
        GLD16(Bp1 + k0, lb1);
        __syncthreads();
        short8 af[4], bfrag[4];
        #pragma unroll
        for (int m = 0; m < 4; ++m)
            af[m] = *(const short8*)(AsB + (wr + m * 16 + lr) * 64 + rsw);
        #pragma unroll
        for (int n = 0; n < 4; ++n)
            bfrag[n] = *(const short8*)(BsB + (wc + n * 16 + lr) * 64 + rsw);
        #pragma unroll
        for (int m = 0; m < 4; ++m)
            #pragma unroll
            for (int n = 0; n < 4; ++n)
                acc[m][n] = __builtin_amdgcn_mfma_f32_16x16x32_bf16(af[m], bfrag[n], acc[m][n], 0, 0, 0);
        __syncthreads();
    }

    // ---- logits epilogue: stage XL/XR 32-col strips into reused As/Bs ----
    const int hh = col0 >> 9;
    float attv[4];
    #pragma unroll
    for (int n = 0; n < 4; ++n)
        attv[n] = att[hh * 512 + ((col0 + wc + n * 16 + lr) & 511)];
    float part[4][4];
    #pragma unroll
    for (int m = 0; m < 4; ++m)
        #pragma unroll
        for (int r = 0; r < 4; ++r) part[m][r] = 0.f;

    const int prt = (lane & 3) * 8;   // 8-elem sub-chunk within 32-col strip
    #pragma unroll
    for (int ch = 0; ch < 4; ++ch) {
        __syncthreads();   // previous strip/tile reads done
        int cc = col0 + ch * 32;
        GLD16(XL + (size_t)srcs[r0] * 2048 + cc + prt, la0);
        GLD16(XL + (size_t)srcs[r0 + 64] * 2048 + cc + prt, la1);
        GLD16(XR + (size_t)dsts[r0] * 2048 + cc + prt, lb0);
        GLD16(XR + (size_t)dsts[r0 + 64] * 2048 + cc + prt, lb1);
        __syncthreads();
        #pragma unroll
        for (int n = 0; n < 4; ++n) {
            if (((wc + n * 16) >> 5) != ch) continue;
            int colin = ((n & 1) << 4) + lr;
            #pragma unroll
            for (int m = 0; m < 4; ++m) {
                #pragma unroll
                for (int r = 0; r < 4; ++r) {
                    int row = wr + m * 16 + lg * 4 + r;
                    float xl = bfu(*(const unsigned short*)(AsB + row * 64 + colin * 2));
                    float xr = bfu(*(const unsigned short*)(BsB + row * 64 + colin * 2));
                    float mv = acc[m][n][r] + xl + xr;
                    part[m][r] += attv[n] * ((mv > 0.f) ? mv : 0.2f * mv);
                }
            }
        }
    }
    #pragma unroll
    for (int m = 0; m < 4; ++m) {
        #pragma unroll
        for (int r = 0; r < 4; ++r) {
            float p = part[m][r];
            p += __shfl_xor(p, 1); p += __shfl_xor(p, 2);
            p += __shfl_xor(p, 4); p += __shfl_xor(p, 8);
            int ge = row0 + wr + m * 16 + lg * 4 + r;
            if (lr == 0 && ge < E) atomicAdd(&logits[ge * 4 + hh], p);
        }
    }
}

// ============ counting sort of edges by dst ============
__global__ __launch_bounds__(256) void count_dst(
    const int* __restrict__ ei, int* __restrict__ cnt, int E)
{
    int e = blockIdx.x * 256 + threadIdx.x;
    if (e < E) atomicAdd(&cnt[ei[E + e]], 1);
}

// single-block hierarchical exclusive scan: offs[0..N], offs[N] = total
__global__ __launch_bounds__(1024) void scan_kernel(
    const int* __restrict__ cnt, int* __restrict__ offs, int N)
{
    __shared__ int wsum[16];
    __shared__ int stot;
    __shared__ int carry_s;
    int t = threadIdx.x, lane = t & 63, w = t >> 6;
    if (t == 0) carry_s = 0;
    __syncthreads();
    for (int base = 0; base < N; base += 1024) {
        int v = (base + t < N) ? cnt[base + t] : 0;
        int x = v;
        #pragma unroll
        for (int off = 1; off < 64; off <<= 1) {
            int y = __shfl_up(x, off);
            if (lane >= off) x += y;
        }
        if (lane == 63) wsum[w] = x;
        __syncthreads();                       // (A) wsum ready
        if (w == 0 && lane < 16) {
            int v0 = wsum[lane];
            int s = v0;
            #pragma unroll
            for (int off = 1; off < 16; off <<= 1) {
                int y = __shfl_up(s, off);
                if (lane >= off) s += y;
            }
            wsum[lane] = s - v0;               // exclusive prefix of wave sums
            if (lane == 15) stot = s;          // chunk total
        }
        __syncthreads();                       // (B) wsum/stot ready
        if (base + t < N) offs[base + t] = carry_s + wsum[w] + x - v;
        __syncthreads();                       // (C) carry_s reads done
        if (t == 0) carry_s += stot;
    }
    __syncthreads();
    if (t == 0) offs[N] = carry_s;
}

__global__ __launch_bounds__(256) void fill_elist(
    const int* __restrict__ ei, const int* __restrict__ offs,
    int* __restrict__ cnt2, int* __restrict__ elist, int E)
{
    int e = blockIdx.x * 256 + threadIdx.x;
    if (e >= E) return;
    int d = ei[E + e];
    int p = offs[d] + atomicAdd(&cnt2[d], 1);
    elist[p] = e;
}

// ============ fused: softmax + gather-aggregate(Y) + relu + GEMV + sigmoid =====
// one wave per dst node; 4 dsts per 256-thread block
__global__ __launch_bounds__(256) void gat_out(
    const __hip_bfloat16* __restrict__ Y,     // [N,4,512] bf16
    const int* __restrict__ ei,
    const int* __restrict__ elist, const int* __restrict__ offs,
    const float* __restrict__ logits,
    const float* __restrict__ bias2,
    const float* __restrict__ Wd2,            // [512,6]
    const float* __restrict__ bd2,
    float* __restrict__ out, int N, int E)
{
    __shared__ float wds[512 * 6];   // 12 KB
    int t = threadIdx.x;
    for (int i = t; i < 512 * 6; i += 256) wds[i] = Wd2[i];
    __syncthreads();
    int w = t >> 6, lane = t & 63;
    int dst = blockIdx.x * 4 + w;
    if (dst >= N) return;
    int s = offs[dst], cntE = offs[dst + 1] - s;

    float den[4] = {0.f, 0.f, 0.f, 0.f};
    for (int i = 0; i < cntE; ++i) {
        int e = elist[s + i];
        #pragma unroll
        for (int h = 0; h < 4; ++h) den[h] += expf(logits[e * 4 + h]);
    }
    float acc[8] = {0.f, 0.f, 0.f, 0.f, 0.f, 0.f, 0.f, 0.f};
    for (int i = 0; i < cntE; ++i) {
        int e = elist[s + i];
        int src = ei[e];
        #pragma unroll
        for (int h = 0; h < 4; ++h) {
            float al = expf(logits[e * 4 + h]) / (den[h] + 1e-16f);
            uint4 q = *(const uint4*)((const unsigned short*)Y
                        + ((size_t)src * 4 + h) * 512 + lane * 8);
            acc[0] += al * bfu((unsigned short)(q.x & 0xffff));
            acc[1] += al * bfu((unsigned short)(q.x >> 16));
            acc[2] += al * bfu((unsigned short)(q.y & 0xffff));
            acc[3] += al * bfu((unsigned short)(q.y >> 16));
            acc[4] += al * bfu((unsigned short)(q.z & 0xffff));
            acc[5] += al * bfu((unsigned short)(q.z >> 16));
            acc[6] += al * bfu((unsigned short)(q.w & 0xffff));
            acc[7] += al * bfu((unsigned short)(q.w >> 16));
        }
    }
    float p[6] = {0.f, 0.f, 0.f, 0.f, 0.f, 0.f};
    #pragma unroll
    for (int j = 0; j < 8; ++j) {
        int c = lane * 8 + j;
        float u = fmaxf(acc[j] + bias2[c], 0.f);
        #pragma unroll
        for (int jj = 0; jj < 6; ++jj) p[jj] += u * wds[c * 6 + jj];
    }
    #pragma unroll
    for (int off = 32; off; off >>= 1)
        #pragma unroll
        for (int jj = 0; jj < 6; ++jj) p[jj] += __shfl_down(p[jj], off);
    if (lane == 0) {
        #pragma unroll
        for (int jj = 0; jj < 6; ++jj)
            out[(size_t)dst * 6 + jj] = 1.f / (1.f + expf(-(p[jj] + bd2[jj])));
    }
}

// ============ bias2 = b_d1 + conv_bias @ W_d1 ============
__global__ __launch_bounds__(256) void bias2_kernel(
    const float* __restrict__ bd1, const float* __restrict__ cb,
    const float* __restrict__ Wd1, float* __restrict__ bias2)
{
    int j = blockIdx.x * 256 + threadIdx.x;
    if (j >= 512) return;
    float acc = bd1[j];
    for (int k = 0; k < 2048; ++k) acc += cb[k] * Wd1[(size_t)k * 512 + j];
    bias2[j] = acc;
}

extern "C" void kernel_launch(void* const* d_in, const int* in_sizes, int n_in,
                              void* d_out, int out_size, void* d_ws, size_t ws_size,
                              hipStream_t stream)
{
    const float* x         = (const float*)d_in[0];
    const float* edge_attr = (const float*)d_in[1];
    const int*   ei        = (const int*)d_in[2];
    const float* W_node = (const float*)d_in[3],  *b_node = (const float*)d_in[4];
    const float* W_edge = (const float*)d_in[5],  *b_edge = (const float*)d_in[6];
    const float* W_l    = (const float*)d_in[7],  *b_l    = (const float*)d_in[8];
    const float* W_r    = (const float*)d_in[9],  *b_r    = (const float*)d_in[10];
    const float* W_le   = (const float*)d_in[11];
    const float* att    = (const float*)d_in[12];
    const float* conv_bias = (const float*)d_in[13];
    const float* W_d1   = (const float*)d_in[14], *b_d1 = (const float*)d_in[15];
    const float* W_d2   = (const float*)d_in[16], *b_d2 = (const float*)d_in[17];
    float* out = (float*)d_out;

    const int N = in_sizes[0] / 7;   // 25000
    const int E = in_sizes[1] / 2;   // 50000
    const int MP = (N + 127) & ~127; // padded rows (unguarded async A-reads)
    const int EP = (E + 127) & ~127;

    // ---- workspace layout (~267 MB) ----
    char* ws = (char*)d_ws;
    const size_t szR0 = (size_t)EP * 512 * 2;     // h bf16[MP,512] then ea bf16[EP,512]
    const size_t szX  = (size_t)MP * 2048 * 2;
    const size_t szW  = (size_t)2048 * 512 * 2;
    const size_t szlg = (size_t)E * 4 * 4;
    const size_t szI  = (((size_t)(N + 1) * 4) + 15) & ~(size_t)15;
    const size_t o_XL = szR0;
    const size_t o_XR = o_XL + szX;
    const size_t o_W  = o_XR + szX;
    const size_t o_lg = o_W + 4 * szW;
    const size_t o_b2 = o_lg + szlg;
    const size_t o_cnt = o_b2 + 2048;
    const size_t o_cnt2 = o_cnt + szI;
    const size_t o_off = o_cnt2 + szI;
    const size_t o_el = o_off + szI;
    const size_t need = o_el + (size_t)E * 4;
    if (ws_size < need) return;   // clean diagnostic failure if ws too small

    __hip_bfloat16* h   = (__hip_bfloat16*)ws;
    __hip_bfloat16* ea  = (__hip_bfloat16*)ws;
    __hip_bfloat16* XL  = (__hip_bfloat16*)(ws + o_XL);
    __hip_bfloat16* XR  = (__hip_bfloat16*)(ws + o_XR);
    __hip_bfloat16* Y   = XR;                       // overlays XR after logits
    __hip_bfloat16* WlT = (__hip_bfloat16*)(ws + o_W);
    __hip_bfloat16* WrT = WlT + szW / 2;
    __hip_bfloat16* WleT= WrT + szW / 2;
    __hip_bfloat16* Wd1T= WleT + szW / 2;
    float* logits = (float*)(ws + o_lg);
    float* bias2  = (float*)(ws + o_b2);
    int* cnt   = (int*)(ws + o_cnt);
    int* cnt2  = (int*)(ws + o_cnt2);
    int* offs  = (int*)(ws + o_off);
    int* elist = (int*)(ws + o_el);

    hipMemsetAsync(logits, 0, szlg, stream);
    hipMemsetAsync(cnt, 0, szI, stream);
    hipMemsetAsync(cnt2, 0, szI, stream);

    // weight prep: [K,N] fp32 -> [N,K] bf16
    dim3 gT(512 / 32, 2048 / 32);
    transpose_bf16<<<gT, 256, 0, stream>>>(W_l,  WlT, 512, 2048);
    transpose_bf16<<<gT, 256, 0, stream>>>(W_r,  WrT, 512, 2048);
    transpose_bf16<<<gT, 256, 0, stream>>>(W_le, WleT, 512, 2048);
    dim3 gT2(2048 / 32, 512 / 32);
    transpose_bf16<<<gT2, 256, 0, stream>>>(W_d1, Wd1T, 2048, 512);
    bias2_kernel<<<2, 256, 0, stream>>>(b_d1, conv_bias, W_d1, bias2);

    // counting sort of edges by dst (only needs ei)
    count_dst<<<(E + 255) / 256, 256, 0, stream>>>(ei, cnt, E);
    scan_kernel<<<1, 1024, 0, stream>>>(cnt, offs, N);
    fill_elist<<<(E + 255) / 256, 256, 0, stream>>>(ei, offs, cnt2, elist, E);

    encode_nodes<<<(N * 512 + 255) / 256, 256, 0, stream>>>(x, W_node, b_node, h, N);

    const int MB = MP / 128;
    dim3 gNode(2048 / 128, MB);                       // x = col tile (fast)
    mfma_gemm<__hip_bfloat16, true><<<gNode, 256, 0, stream>>>(
        h, 512, 0, WlT, 512, 0, b_l, XL, 2048, 0, N, 512);
    mfma_gemm<__hip_bfloat16, true><<<gNode, 256, 0, stream>>>(
        h, 512, 0, WrT, 512, 0, b_r, XR, 2048, 0, N, 512);

    // h dead -> region0 becomes ea
    encode_edges<<<(E * 512 + 255) / 256, 256, 0, stream>>>(edge_attr, W_edge, b_edge, ea, E);

    dim3 gE(16, EP / 128);                            // x = col tile (fast)
    edge_mfma_logits<<<gE, 256, 0, stream>>>(ea, WleT, XL, XR, ei, att, logits, E);

    // Y[n, hh*512+c] = XL[n, hh*512:] @ W_d1[hh*512:, :]  (block-diag, grid.z=4)
    dim3 gY(512 / 128, MB, 4);
    mfma_gemm<__hip_bfloat16, false><<<gY, 256, 0, stream>>>(
        XL, 2048, 512, Wd1T, 2048, 512, nullptr, Y, 2048, 512, N, 512);

    gat_out<<<(N + 3) / 4, 256, 0, stream>>>(Y, ei, elist, offs, logits,
                                             bias2, W_d2, b_d2, out, N, E);
}